// Round 10
// baseline (319.079 us; speedup 1.0000x reference)
//
#include <hip/hip_runtime.h>

// VectorQuantizer forward (VQ-VAE), MI355X/gfx950 — round 10.
// Numerics IDENTICAL to passing rounds 3/4/6: per-(row,k) serial ascending-j
// f32 FMA chain, d = fl32(fl32(s1+s2_k) - 2*acc), strict-< first-index
// argmin, numpy-pairwise s1/s2. Codebook via wave-uniform s_load_dwordx16
// -> SGPR operand of v_fma_f32 (scalar pipe; zero LDS in main loop).
//
// Round-10 changes vs round 9 (both target the AGPR-parking junk that
// rounds 4/6 measured as ~2.1x VALU issue bloat at VGPR_Count=40):
//  1. Row unpacked to 64 SCALAR floats. gfx950's backend rejects any
//     multi-register tuple (float4) as an asm operand ("indirect register
//     inputs"); scalar f32 "v" operands are the supported keep-live idiom.
//     Pins: 4 x asm volatile("" :: "v"(..x16 scalars..)) per iteration.
//  2. amdgpu_waves_per_eu(4,4): capping MAX waves/EU at 4 makes arch-VGPR
//     use below 128 worthless for occupancy, deleting the allocator's
//     motive to park the row in AGPRs at all.

#define NROWS (64 * 4096)            // 262144
#define DIMS 64
#define KCODES 512
#define BLOCK 256                    // 4 waves
#define GRID (NROWS / BLOCK)         // 1024 blocks, 1 row/thread
#define WS_S2_OFF 0                  // 512 floats
#define WS_RED_OFF 4096              // GRID doubles

typedef unsigned int u16v __attribute__((ext_vector_type(16)));

// numpy pairwise sum, n=64, scalar path: 8 strided accumulators, serial in i,
// then ((r0+r1)+(r2+r3)) + ((r4+r5)+(r6+r7)).  (unchanged; used by vq_s2)
__device__ __forceinline__ float pairwise64_sq(const float4* v) {
  float a[64];
  #pragma unroll
  for (int c = 0; c < 16; ++c) {
    a[4 * c + 0] = v[c].x * v[c].x;
    a[4 * c + 1] = v[c].y * v[c].y;
    a[4 * c + 2] = v[c].z * v[c].z;
    a[4 * c + 3] = v[c].w * v[c].w;
  }
  float r0 = a[0], r1 = a[1], r2 = a[2], r3 = a[3];
  float r4 = a[4], r5 = a[5], r6 = a[6], r7 = a[7];
  #pragma unroll
  for (int i = 8; i < 64; i += 8) {
    r0 += a[i + 0]; r1 += a[i + 1]; r2 += a[i + 2]; r3 += a[i + 3];
    r4 += a[i + 4]; r5 += a[i + 5]; r6 += a[i + 6]; r7 += a[i + 7];
  }
  return ((r0 + r1) + (r2 + r3)) + ((r4 + r5) + (r6 + r7));
}

// s2_k = numpy-pairwise sum(emb_k^2), precomputed once (bit-identical).
__global__ void vq_s2(const float* __restrict__ emb, float* __restrict__ s2) {
  int k = blockIdx.x * 256 + threadIdx.x;   // grid 2 x 256 = 512
  const float4* row = (const float4*)(emb + (size_t)k * DIMS);
  float4 r[16];
  #pragma unroll
  for (int c = 0; c < 16; ++c) r[c] = row[c];
  s2[k] = pairwise64_sq(r);
}

// One FMA: acc = fma(xa[l], E[j], acc) with E element in SGPR.
#define FMA1(E, j, l) acc = fmaf(xa[l], __uint_as_float(E[j]), acc);

#define FMA16(E, l0)                                                     \
  FMA1(E, 0, (l0) + 0)   FMA1(E, 1, (l0) + 1)   FMA1(E, 2, (l0) + 2)     \
  FMA1(E, 3, (l0) + 3)   FMA1(E, 4, (l0) + 4)   FMA1(E, 5, (l0) + 5)     \
  FMA1(E, 6, (l0) + 6)   FMA1(E, 7, (l0) + 7)   FMA1(E, 8, (l0) + 8)     \
  FMA1(E, 9, (l0) + 9)   FMA1(E, 10, (l0) + 10) FMA1(E, 11, (l0) + 11)   \
  FMA1(E, 12, (l0) + 12) FMA1(E, 13, (l0) + 13) FMA1(E, 14, (l0) + 14)   \
  FMA1(E, 15, (l0) + 15)

// Pin 16 scalar floats into arch VGPRs (scalar "v" operands only —
// gfx950 backend rejects multi-register tuple asm operands).
#define PIN16(l0)                                                        \
  asm volatile("" :: "v"(xa[(l0) + 0]), "v"(xa[(l0) + 1]),               \
                     "v"(xa[(l0) + 2]), "v"(xa[(l0) + 3]),               \
                     "v"(xa[(l0) + 4]), "v"(xa[(l0) + 5]),               \
                     "v"(xa[(l0) + 6]), "v"(xa[(l0) + 7]),               \
                     "v"(xa[(l0) + 8]), "v"(xa[(l0) + 9]),               \
                     "v"(xa[(l0) + 10]), "v"(xa[(l0) + 11]),             \
                     "v"(xa[(l0) + 12]), "v"(xa[(l0) + 13]),             \
                     "v"(xa[(l0) + 14]), "v"(xa[(l0) + 15]));

__global__ __launch_bounds__(BLOCK)
__attribute__((amdgpu_waves_per_eu(4, 4)))
void vq_main(
    const float* __restrict__ x, const float* __restrict__ emb,
    const float* __restrict__ s2, float* __restrict__ out_idx,
    float* __restrict__ out_q, double* __restrict__ ws) {
  __shared__ int   kidx[BLOCK];
  __shared__ double red[BLOCK / 64];
  const int tid = threadIdx.x;
  const int row0 = blockIdx.x * BLOCK;
  const int r = row0 + tid;

  // ---- my row: float4 loads, unpacked to 64 scalar SSA values ----
  float xa[64];
  {
    const float4* p = (const float4*)(x + (size_t)r * DIMS);
    #pragma unroll
    for (int c = 0; c < 16; ++c) {
      float4 t = p[c];
      xa[4 * c + 0] = t.x; xa[4 * c + 1] = t.y;
      xa[4 * c + 2] = t.z; xa[4 * c + 3] = t.w;
    }
  }

  // ---- s1 = numpy-pairwise sum(x^2): same op order as pairwise64_sq ----
  float r0 = xa[0] * xa[0], r1 = xa[1] * xa[1];
  float r2 = xa[2] * xa[2], r3 = xa[3] * xa[3];
  float r4 = xa[4] * xa[4], r5 = xa[5] * xa[5];
  float r6 = xa[6] * xa[6], r7 = xa[7] * xa[7];
  #pragma unroll
  for (int i = 8; i < 64; i += 8) {
    r0 += xa[i + 0] * xa[i + 0]; r1 += xa[i + 1] * xa[i + 1];
    r2 += xa[i + 2] * xa[i + 2]; r3 += xa[i + 3] * xa[i + 3];
    r4 += xa[i + 4] * xa[i + 4]; r5 += xa[i + 5] * xa[i + 5];
    r6 += xa[i + 6] * xa[i + 6]; r7 += xa[i + 7] * xa[i + 7];
  }
  const float s1 = ((r0 + r1) + (r2 + r3)) + ((r4 + r5) + (r6 + r7));

  // ---- scan all codes; codebook rows via scalar pipe (wave-uniform) ----
  float d1 = 3.4e38f;
  int kbest = 0;
  #pragma unroll 1
  for (int k = 0; k < KCODES; ++k) {
    PIN16(0) PIN16(16) PIN16(32) PIN16(48)

    const float* pe = emb + (size_t)k * DIMS;   // wave-uniform address
    const float* ps = s2 + k;
    u16v e0, e1, e2, e3;
    unsigned int bku;
    asm volatile(
        "s_load_dwordx16 %0, %5, 0x0\n\t"
        "s_load_dwordx16 %1, %5, 0x40\n\t"
        "s_load_dwordx16 %2, %5, 0x80\n\t"
        "s_load_dwordx16 %3, %5, 0xc0\n\t"
        "s_load_dword    %4, %6, 0x0\n\t"
        "s_waitcnt lgkmcnt(0)"
        : "=&s"(e0), "=&s"(e1), "=&s"(e2), "=&s"(e3), "=&s"(bku)
        : "s"(pe), "s"(ps));

    float acc = 0.f;                 // SERIAL ascending-j FMA chain (as r3)
    FMA16(e0, 0) FMA16(e1, 16) FMA16(e2, 32) FMA16(e3, 48)

    float S = s1 + __uint_as_float(bku);  // fl32(s1 + s2_k)
    float d = fmaf(-2.0f, acc, S);        // fl32(S - 2*acc), 2*acc exact
    if (d < d1) { d1 = d; kbest = k; }    // strict <: first index wins ties
  }

  out_idx[r] = (float)kbest;
  kidx[tid] = kbest;

  // ---- loss: d1 IS ||x - e_best||^2 up to ~1.5e-5 abs (loss ~ 1.0) ----
  double lsum = (double)d1;
  #pragma unroll
  for (int off = 32; off > 0; off >>= 1) lsum += __shfl_down(lsum, off);
  if ((tid & 63) == 0) red[tid >> 6] = lsum;

  __syncthreads();

  if (tid == 0) {
    double s = 0.0;
    #pragma unroll
    for (int w = 0; w < BLOCK / 64; ++w) s += red[w];
    ws[blockIdx.x] = s;   // written every launch -> no init needed
  }

  // ---- coalesced out_q: gather codebook rows from L2 via LDS kidx ----
  const float4* emb4 = (const float4*)emb;
  float4* outq4 = (float4*)out_q;
  #pragma unroll
  for (int it = 0; it < 16; ++it) {
    int idx = it * BLOCK + tid;        // 0..4095
    int rr = idx >> 4, c = idx & 15;   // 16 consecutive lanes share one row
    float4 v = emb4[(size_t)kidx[rr] * 16 + c];
    outq4[(size_t)(row0 + rr) * 16 + c] = v;
  }
}

__global__ void vq_loss_finalize(const double* __restrict__ ws,
                                 float* __restrict__ out_loss) {
  double s = 0.0;
  for (int i = threadIdx.x; i < GRID; i += 64) s += ws[i];
  #pragma unroll
  for (int off = 32; off > 0; off >>= 1) s += __shfl_down(s, off);
  if (threadIdx.x == 0)
    *out_loss = (float)(1.25 * s / (double)((size_t)NROWS * DIMS));
}

extern "C" void kernel_launch(void* const* d_in, const int* in_sizes, int n_in,
                              void* d_out, int out_size, void* d_ws, size_t ws_size,
                              hipStream_t stream) {
  (void)in_sizes; (void)n_in; (void)out_size; (void)ws_size;
  const float* x   = (const float*)d_in[0];
  const float* emb = (const float*)d_in[1];
  float* out      = (float*)d_out;
  float* out_idx  = out;                                  // NROWS
  float* out_q    = out + NROWS;                          // NROWS*DIMS
  float* out_loss = out + NROWS + (size_t)NROWS * DIMS;   // 1
  float*  ws_s2  = (float*)((char*)d_ws + WS_S2_OFF);     // 512 floats
  double* ws_red = (double*)((char*)d_ws + WS_RED_OFF);   // GRID doubles

  vq_s2<<<2, 256, 0, stream>>>(emb, ws_s2);
  vq_main<<<GRID, BLOCK, 0, stream>>>(x, emb, ws_s2, out_idx, out_q, ws_red);
  vq_loss_finalize<<<1, 64, 0, stream>>>(ws_red, out_loss);
}